// Round 4
// baseline (501.617 us; speedup 1.0000x reference)
//
#include <hip/hip_runtime.h>

// StrictProjectionBlock: per-3x3-matrix Frobenius normalize + 4 Newton-Schulz
// layers (Q' = Q*M, M = (0.5N-1.5I)N + 2I, N = Q^T Q — symmetric, 6 entries).
//
// History: R1 (1 mat/thread, LDS both ways, 3 barriers) = 90us. R3 (algebra
// cut, VALUBusy 52->37%) = 86us -> NOT VALU-bound; all pipes <40% busy ->
// latency/dependency-bound (1 serial chain per thread).
//
// R4: 4 matrices per thread.
//  * Thread's 4 consecutive matrices = 36 floats = 144B, 16B-aligned:
//    LDS reads become 9x ds_read_b128 (stride-144B across lanes hits all 32
//    banks evenly, 8 hits each — balanced -> full LDS BW), and results are
//    stored DIRECT to global as 9x dwordx4 per thread (no output LDS
//    round-trip, no second barrier).
//  * 4 independent dependency chains per thread (4x ILP), 4x fewer waves.
//  * Input staging stays perfectly coalesced: 256 threads x 9 float4.
//  * LDS 36864B -> 4 blocks/CU = 16 waves/CU; but 4096 matrices in flight
//    per CU vs ~1300 before.
// Tail: 4M matrices / 4 = 1,000,000 threads = 3906.25 blocks -> 3907 blocks,
// per-thread guard (nmat % 4 == 0 so a thread is all-or-nothing).

#define NLAYERS 4
#define MPT 4

typedef float v4f __attribute__((ext_vector_type(4)));

__global__ __launch_bounds__(256) void
proj_kernel(const float* __restrict__ x, float* __restrict__ out,
            int n_active_threads, int total_f4) {
    __shared__ float lin[256 * 9 * MPT];         // 36864 B
    const int tid = threadIdx.x;
    const long long t_global = (long long)blockIdx.x * 256 + tid;
    const long long bb4 = (long long)blockIdx.x * (256 * 9);  // block's first float4

    // ---- stage 1024 matrices = 2304 float4, coalesced ----
    const v4f* __restrict__ gin = (const v4f*)x;
    v4f* lin4 = (v4f*)lin;
#pragma unroll
    for (int j = 0; j < 9; ++j) {
        const long long idx = bb4 + tid + 256 * j;
        if (idx < total_f4) lin4[tid + 256 * j] = gin[idx];
    }
    __syncthreads();

    if (t_global >= n_active_threads) return;

    // ---- this thread's 4 matrices: 36 contiguous floats, 16B-aligned ----
    float buf[9 * MPT];
    {
        v4f* b4 = (v4f*)buf;
        const v4f* src = (const v4f*)(lin + tid * (9 * MPT));
#pragma unroll
        for (int j = 0; j < 9; ++j) b4[j] = src[j];   // 9x ds_read_b128
    }

#pragma unroll
    for (int m = 0; m < MPT; ++m) {
        float q[9];
#pragma unroll
        for (int k = 0; k < 9; ++k) q[k] = buf[9 * m + k];

        // Frobenius normalize
        float s = 0.f;
#pragma unroll
        for (int k = 0; k < 9; ++k) s = __builtin_fmaf(q[k], q[k], s);
        const float inv = rsqrtf(s);
#pragma unroll
        for (int k = 0; k < 9; ++k) q[k] *= inv;

        // 4 Newton-Schulz layers: Q <- Q * ((0.5N - 1.5I)N + 2I)
#pragma unroll
        for (int layer = 0; layer < NLAYERS; ++layer) {
            const float n00 = q[0]*q[0] + q[3]*q[3] + q[6]*q[6];
            const float n01 = q[0]*q[1] + q[3]*q[4] + q[6]*q[7];
            const float n02 = q[0]*q[2] + q[3]*q[5] + q[6]*q[8];
            const float n11 = q[1]*q[1] + q[4]*q[4] + q[7]*q[7];
            const float n12 = q[1]*q[2] + q[4]*q[5] + q[7]*q[8];
            const float n22 = q[2]*q[2] + q[5]*q[5] + q[8]*q[8];

            const float a00 = __builtin_fmaf(0.5f, n00, -1.5f);
            const float a11 = __builtin_fmaf(0.5f, n11, -1.5f);
            const float a22 = __builtin_fmaf(0.5f, n22, -1.5f);
            const float a01 = 0.5f * n01;
            const float a02 = 0.5f * n02;
            const float a12 = 0.5f * n12;

            const float m00 = __builtin_fmaf(a00,n00, __builtin_fmaf(a01,n01, __builtin_fmaf(a02,n02, 2.0f)));
            const float m01 = __builtin_fmaf(a00,n01, __builtin_fmaf(a01,n11, a02*n12));
            const float m02 = __builtin_fmaf(a00,n02, __builtin_fmaf(a01,n12, a02*n22));
            const float m11 = __builtin_fmaf(a01,n01, __builtin_fmaf(a11,n11, __builtin_fmaf(a12,n12, 2.0f)));
            const float m12 = __builtin_fmaf(a01,n02, __builtin_fmaf(a11,n12, a12*n22));
            const float m22 = __builtin_fmaf(a02,n02, __builtin_fmaf(a12,n12, __builtin_fmaf(a22,n22, 2.0f)));

            const float M[3][3] = {{m00, m01, m02}, {m01, m11, m12}, {m02, m12, m22}};

            float qn[9];
#pragma unroll
            for (int i = 0; i < 3; ++i)
#pragma unroll
                for (int j = 0; j < 3; ++j)
                    qn[3*i+j] = __builtin_fmaf(q[3*i+0], M[0][j],
                                __builtin_fmaf(q[3*i+1], M[1][j],
                                               q[3*i+2] * M[2][j]));
#pragma unroll
            for (int k = 0; k < 9; ++k) q[k] = qn[k];
        }

#pragma unroll
        for (int k = 0; k < 9; ++k) buf[9 * m + k] = q[k];
    }

    // ---- direct 16B-aligned stores: 9x global_store_dwordx4 ----
    v4f* __restrict__ dst = (v4f*)(out + t_global * (9 * MPT));
    const v4f* b4 = (const v4f*)buf;
#pragma unroll
    for (int j = 0; j < 9; ++j)
        __builtin_nontemporal_store(b4[j], dst + j);
}

extern "C" void kernel_launch(void* const* d_in, const int* in_sizes, int n_in,
                              void* d_out, int out_size, void* d_ws, size_t ws_size,
                              hipStream_t stream) {
    const float* x = (const float*)d_in[0];
    float* out = (float*)d_out;
    const int nmat = in_sizes[0] / 9;                 // 4,000,000
    const int n_active = nmat / MPT;                  // 1,000,000 threads
    const int total_f4 = (nmat * 9) / 4;              // 9,000,000 float4 loads
    const int blocks = (n_active + 255) / 256;        // 3907
    proj_kernel<<<blocks, 256, 0, stream>>>(x, out, n_active, total_f4);
}